// Round 2
// baseline (284.682 us; speedup 1.0000x reference)
//
#include <hip/hip_runtime.h>
#include <math.h>

#define B_ROWS 4096
#define D_DIM  1024
static constexpr float TEMP = 0.2f;
static constexpr float FP8_SCALE = 16.0f;        // per-side scale before cast
static constexpr float INV_S2 = 1.0f / 256.0f;   // 1/SCALE^2: acc -> sim

typedef __attribute__((ext_vector_type(4)))  int   i32x4;
typedef __attribute__((ext_vector_type(8)))  int   i32x8;
typedef __attribute__((ext_vector_type(16))) float f32x16;

// float -> OCP e4m3fn byte, RNE. Data path: |f| <= ~4, no NaN/inf.
__device__ inline unsigned char f2fp8(float f) {
    unsigned int u = __float_as_uint(f);
    unsigned int s = (u >> 24) & 0x80u;
    float af = fabsf(f);
    unsigned char b;
    if (af >= 0x1.0p-6f) {                 // normal e4m3 range
        unsigned int au = u & 0x7fffffffu;
        unsigned int lsb = (au >> 20) & 1u;
        au += 0x7ffffu + lsb;              // RNE into 3 mantissa bits
        int e = (int)(au >> 23) - 127 + 7;
        unsigned int m = (au >> 20) & 7u;
        if (e > 15 || (e == 15 && m > 6)) b = 0x7e;   // saturate 448
        else b = (unsigned char)((e << 3) | m);
    } else {                               // subnormal: quantum 2^-9
        int q = (int)rintf(af * 512.0f);
        b = (unsigned char)(q >= 8 ? 0x08 : q);
    }
    return (unsigned char)(b | s);
}

__device__ inline unsigned int f2fp8x4(float4 v) {
    return (unsigned int)f2fp8(v.x)
         | ((unsigned int)f2fp8(v.y) << 8)
         | ((unsigned int)f2fp8(v.z) << 16)
         | ((unsigned int)f2fp8(v.w) << 24);
}

// async global->LDS, 16 B/lane; LDS dest = wave-uniform base + lane*16
__device__ inline void gload_lds16(const unsigned char* g, unsigned char* l) {
    __builtin_amdgcn_global_load_lds(
        (const __attribute__((address_space(1))) unsigned int*)g,
        (__attribute__((address_space(3))) unsigned int*)l,
        16, 0, 0);
}

// read one 32-B fragment (two swizzled 16-B pieces) -> v8i32 MFMA operand
__device__ inline i32x8 read_frag(const unsigned char* p, int o0, int o1) {
    i32x4 lo = *(const i32x4*)(p + o0);
    i32x4 hi = *(const i32x4*)(p + o1);
    return __builtin_shufflevector(lo, hi, 0, 1, 2, 3, 4, 5, 6, 7);
}

// MX-scaled fp8 x fp8, unit E8M0 scales (0x7f = 2^0): plain fp8 GEMM at 2x rate
#define MX_MFMA(A, Bv, C) __builtin_amdgcn_mfma_scale_f32_32x32x64_f8f6f4( \
    (A), (Bv), (C), 0, 0, 0, 0x7f7f7f7f, 0, 0x7f7f7f7f)

// ws layout: w[0]=pos acc, w[1]=neg acc, w[2]=finalize ticket (u32),
//            then Zi8 (4096x1024 fp8) at byte (w+16), Zj8 after.

// Wave-per-row normalize (fp32) + scale by 16 + cast to fp8 e4m3.
__global__ __launch_bounds__(256) void norm_cast_kernel(
        const float* __restrict__ emb_i, const float* __restrict__ emb_j,
        unsigned char* __restrict__ Zi8, unsigned char* __restrict__ Zj8,
        float* __restrict__ w) {
    const int tid = threadIdx.x;
    if (blockIdx.x == 0 && tid == 0) {
        w[0] = 0.0f; w[1] = 0.0f;
        ((unsigned int*)w)[2] = 0u;
    }
    const int wave = tid >> 6, lane = tid & 63;
    const int row = blockIdx.x * 4 + wave;          // 0..8191
    const float* src; unsigned char* dst; int r;
    if (row < B_ROWS) { src = emb_i; dst = Zi8; r = row; }
    else              { src = emb_j; dst = Zj8; r = row - B_ROWS; }

    const float4* p = (const float4*)(src + (size_t)r * D_DIM);
    float4 v0 = p[lane], v1 = p[64 + lane], v2 = p[128 + lane], v3 = p[192 + lane];
    float s = v0.x*v0.x + v0.y*v0.y + v0.z*v0.z + v0.w*v0.w
            + v1.x*v1.x + v1.y*v1.y + v1.z*v1.z + v1.w*v1.w
            + v2.x*v2.x + v2.y*v2.y + v2.z*v2.z + v2.w*v2.w
            + v3.x*v3.x + v3.y*v3.y + v3.z*v3.z + v3.w*v3.w;
    #pragma unroll
    for (int m = 1; m < 64; m <<= 1) s += __shfl_xor(s, m, 64);
    const float inv = FP8_SCALE / fmaxf(sqrtf(s), 1e-12f);

    float4 a0 = {v0.x*inv, v0.y*inv, v0.z*inv, v0.w*inv};
    float4 a1 = {v1.x*inv, v1.y*inv, v1.z*inv, v1.w*inv};
    float4 a2 = {v2.x*inv, v2.y*inv, v2.z*inv, v2.w*inv};
    float4 a3 = {v3.x*inv, v3.y*inv, v3.z*inv, v3.w*inv};
    unsigned int* q = (unsigned int*)(dst + (size_t)r * D_DIM);
    q[lane]       = f2fp8x4(a0);
    q[64 + lane]  = f2fp8x4(a1);
    q[128 + lane] = f2fp8x4(a2);
    q[192 + lane] = f2fp8x4(a3);
}

// 128x256 block tile, BK=128 bytes (fp8), 4 waves: wave (wy,wx) owns 64x128 =
// 2x4 MFMA tiles of 32x32x64 MX-fp8 (unit scales), two K-steps per LDS tile.
// Grid 16x32 = 512 blocks = exactly 2 resident/CU. LDS 48 KB single-buffered.
//
// ROUND-0 PROVEN SKELETON: barrier -> STAGE -> barrier -> compute. No fragment
// is live across any barrier (round-1's cross-barrier liveness spilled to
// scratch: 315 MB WRITE_SIZE). Staging latency is exposed but amortized over
// 8 iters with 2 resident blocks/CU.
//
// LDS row = 128 B = 8 x 16-B pieces. XOR swizzle: logical piece c of row r sits
// at physical piece p = c ^ (r&7)  (involution -> conflict-free ds_read_b128;
// verified absmax 0.0 in round 1). global_load_lds writes linearly (lane*16),
// so the *global* source piece is pre-swizzled per lane; LDS stays linear.
__global__ __launch_bounds__(256, 2) void simloss_mfma_mxfp8_kernel(
        const unsigned char* __restrict__ Zi8,
        const unsigned char* __restrict__ Zj8,
        float* __restrict__ w, float* __restrict__ out) {
    __shared__ __align__(16) unsigned char lA[128 * 128];  // 16 KB (Zj rows)
    __shared__ __align__(16) unsigned char lB[256 * 128];  // 32 KB (Zi rows)
    __shared__ float rn[4], rp[4];

    const int tid  = threadIdx.x;
    const int lane = tid & 63;
    const int wave = tid >> 6;
    const int wy = wave >> 1, wx = wave & 1;
    const int rowBase = blockIdx.y * 128;   // a (Zj rows)
    const int colBase = blockIdx.x * 256;   // b (Zi rows)

    // --- staging: chunk = 8 rows x 128 B = 1 KB = one wave-load (16 B/lane).
    //     lane l -> LDS row (l>>3), physical piece (l&7); needs logical piece
    //     c = (l&7) ^ (row&7) = (l&7) ^ ((l>>3)&7) from global.
    const int srow = lane >> 3;
    const int sc   = (lane & 7) ^ (srow & 7);
    const unsigned char* gA = Zj8 + (size_t)(rowBase + 32*wave + srow) * D_DIM + sc*16;
    const unsigned char* gB = Zi8 + (size_t)(colBase + 64*wave + srow) * D_DIM + sc*16;
    unsigned char* sA = lA + wave * 4096;   // wave stages A rows [32w,32w+32)
    unsigned char* sB = lB + wave * 8192;   // wave stages B rows [64w,64w+64)

    // --- fragment addressing: lane l holds row (l&31), k = (l>>5)*32 + 0..31
    //     (one MX scale-block). Logical piece for (kstep kk, 16B-half t) =
    //     kk*4 + (l>>5)*2 + t; physical = c ^ (row&7); row&7 == lane&7 since
    //     every fragment row base is a multiple of 8.
    const int lr = lane & 31;
    const int kh = lane >> 5;
    int off[2][2];
    #pragma unroll
    for (int kk = 0; kk < 2; ++kk)
        #pragma unroll
        for (int t = 0; t < 2; ++t)
            off[kk][t] = ((((kk << 2) + (kh << 1) + t) ^ (lane & 7)) << 4);
    const unsigned char* fA = lA + (wy * 64  + lr) * 128;   // + i*32*128
    const unsigned char* fB = lB + (wx * 128 + lr) * 128;   // + j*32*128

    f32x16 acc[2][4];
    #pragma unroll
    for (int i = 0; i < 2; ++i)
        #pragma unroll
        for (int j = 0; j < 4; ++j)
            #pragma unroll
            for (int r = 0; r < 16; ++r)
                acc[i][j][r] = 0.0f;

    for (int it = 0; it < 8; ++it) {
        __syncthreads();                    // prior readers done
        const int k0 = it * 128;
        #pragma unroll
        for (int n = 0; n < 4; ++n)
            gload_lds16(gA + (size_t)(n*8) * D_DIM + k0, sA + n*1024);
        #pragma unroll
        for (int n = 0; n < 8; ++n)
            gload_lds16(gB + (size_t)(n*8) * D_DIM + k0, sB + n*1024);
        __syncthreads();                    // staging visible (vmcnt drained)

        #pragma unroll
        for (int kk = 0; kk < 2; ++kk) {    // frags never cross a barrier
            i32x8 a0 = read_frag(fA,         off[kk][0], off[kk][1]);
            i32x8 a1 = read_frag(fA + 4096,  off[kk][0], off[kk][1]);
            i32x8 b0 = read_frag(fB,         off[kk][0], off[kk][1]);
            i32x8 b1 = read_frag(fB + 4096,  off[kk][0], off[kk][1]);
            i32x8 b2 = read_frag(fB + 8192,  off[kk][0], off[kk][1]);
            i32x8 b3 = read_frag(fB + 12288, off[kk][0], off[kk][1]);
            acc[0][0] = MX_MFMA(a0, b0, acc[0][0]);
            acc[0][1] = MX_MFMA(a0, b1, acc[0][1]);
            acc[0][2] = MX_MFMA(a0, b2, acc[0][2]);
            acc[0][3] = MX_MFMA(a0, b3, acc[0][3]);
            acc[1][0] = MX_MFMA(a1, b0, acc[1][0]);
            acc[1][1] = MX_MFMA(a1, b1, acc[1][1]);
            acc[1][2] = MX_MFMA(a1, b2, acc[1][2]);
            acc[1][3] = MX_MFMA(a1, b3, acc[1][3]);
        }
    }

    // --- fused epilogue; 32x32 C layout: col=lane&31,
    //     row=(reg&3) + 8*(reg>>2) + 4*(lane>>5)   (verified round 1)
    float neg = 0.f, pos = 0.f;
    const int bc = colBase + wx * 128 + (lane & 31);
    #pragma unroll
    for (int i = 0; i < 2; ++i) {
        const int abase = rowBase + wy * 64 + i * 32 + 4 * kh;
        #pragma unroll
        for (int j = 0; j < 4; ++j) {
            const int b = bc + j * 32;
            #pragma unroll
            for (int r = 0; r < 16; ++r) {
                const int arow = abase + (r & 3) + 8 * (r >> 2);
                const float x = acc[i][j][r] * INV_S2 - TEMP;   // sim - T
                if (arow == b) pos += __logf(1.0f + __expf(-x));
                else           neg += __logf(1.0f + __expf(x));
            }
        }
    }
    #pragma unroll
    for (int o = 32; o > 0; o >>= 1) {
        neg += __shfl_down(neg, o, 64);
        pos += __shfl_down(pos, o, 64);
    }
    if (lane == 0) { rn[wave] = neg; rp[wave] = pos; }
    __syncthreads();
    if (tid == 0) {
        atomicAdd(&w[1], rn[0] + rn[1] + rn[2] + rn[3]);
        if ((int)blockIdx.x == (int)(blockIdx.y >> 1))   // tile holding diagonal
            atomicAdd(&w[0], rp[0] + rp[1] + rp[2] + rp[3]);
        __threadfence();
        unsigned int done = atomicAdd(((unsigned int*)w) + 2, 1u);
        if (done == gridDim.x * gridDim.y - 1) {         // last block finalizes
            const float psum = atomicAdd(&w[0], 0.0f);
            const float nsum = atomicAdd(&w[1], 0.0f);
            out[0] = 0.5f * (psum / (float)B_ROWS)
                   + 0.5f * (nsum / ((float)B_ROWS * (float)(B_ROWS - 1)));
        }
    }
}

extern "C" void kernel_launch(void* const* d_in, const int* in_sizes, int n_in,
                              void* d_out, int out_size, void* d_ws, size_t ws_size,
                              hipStream_t stream) {
    const float* emb_i = (const float*)d_in[0];
    const float* emb_j = (const float*)d_in[1];
    float* w = (float*)d_ws;
    unsigned char* Zi8 = (unsigned char*)(w + 16);
    unsigned char* Zj8 = Zi8 + (size_t)B_ROWS * D_DIM;
    float* out = (float*)d_out;

    norm_cast_kernel<<<2 * B_ROWS / 4, 256, 0, stream>>>(emb_i, emb_j, Zi8, Zj8, w);
    dim3 grid(B_ROWS / 256, B_ROWS / 128);   // 16 x 32 = 512 blocks, 2/CU
    simloss_mfma_mxfp8_kernel<<<grid, 256, 0, stream>>>(Zi8, Zj8, w, out);
}

// Round 3
// 217.566 us; speedup vs baseline: 1.3085x; 1.3085x over previous
//
#include <hip/hip_runtime.h>
#include <math.h>

#define B_ROWS 4096
#define D_DIM  1024
static constexpr float TEMP = 0.2f;
static constexpr float FP8_SCALE = 16.0f;        // per-side scale before cast
static constexpr float INV_S2 = 1.0f / 256.0f;   // 1/SCALE^2: acc -> sim

typedef __attribute__((ext_vector_type(4)))  int   i32x4;
typedef __attribute__((ext_vector_type(8)))  int   i32x8;
typedef __attribute__((ext_vector_type(16))) float f32x16;

// float -> OCP e4m3fn byte, RNE. Data path: |f| <= ~4, no NaN/inf.
__device__ inline unsigned char f2fp8(float f) {
    unsigned int u = __float_as_uint(f);
    unsigned int s = (u >> 24) & 0x80u;
    float af = fabsf(f);
    unsigned char b;
    if (af >= 0x1.0p-6f) {                 // normal e4m3 range
        unsigned int au = u & 0x7fffffffu;
        unsigned int lsb = (au >> 20) & 1u;
        au += 0x7ffffu + lsb;              // RNE into 3 mantissa bits
        int e = (int)(au >> 23) - 127 + 7;
        unsigned int m = (au >> 20) & 7u;
        if (e > 15 || (e == 15 && m > 6)) b = 0x7e;   // saturate 448
        else b = (unsigned char)((e << 3) | m);
    } else {                               // subnormal: quantum 2^-9
        int q = (int)rintf(af * 512.0f);
        b = (unsigned char)(q >= 8 ? 0x08 : q);
    }
    return (unsigned char)(b | s);
}

__device__ inline unsigned int f2fp8x4(float4 v) {
    return (unsigned int)f2fp8(v.x)
         | ((unsigned int)f2fp8(v.y) << 8)
         | ((unsigned int)f2fp8(v.z) << 16)
         | ((unsigned int)f2fp8(v.w) << 24);
}

// async global->LDS, 16 B/lane; LDS dest = wave-uniform base + lane*16
__device__ inline void gload_lds16(const unsigned char* g, unsigned char* l) {
    __builtin_amdgcn_global_load_lds(
        (const __attribute__((address_space(1))) unsigned int*)g,
        (__attribute__((address_space(3))) unsigned int*)l,
        16, 0, 0);
}

// read one 32-B fragment (two swizzled 16-B pieces) -> v8i32 MFMA operand
__device__ inline i32x8 read_frag(const unsigned char* p, int o0, int o1) {
    i32x4 lo = *(const i32x4*)(p + o0);
    i32x4 hi = *(const i32x4*)(p + o1);
    return __builtin_shufflevector(lo, hi, 0, 1, 2, 3, 4, 5, 6, 7);
}

// MX-scaled fp8 x fp8, unit E8M0 scales (0x7f = 2^0): plain fp8 GEMM at 2x rate
#define MX_MFMA(A, Bv, C) __builtin_amdgcn_mfma_scale_f32_32x32x64_f8f6f4( \
    (A), (Bv), (C), 0, 0, 0, 0x7f7f7f7f, 0, 0x7f7f7f7f)

// ws layout: w[0]=pos acc, w[1]=neg acc, w[2]=finalize ticket (u32),
//            then Zi8 (4096x1024 fp8) at byte (w+16), Zj8 after.

// Wave-per-row normalize (fp32) + scale by 16 + cast to fp8 e4m3.
__global__ __launch_bounds__(256) void norm_cast_kernel(
        const float* __restrict__ emb_i, const float* __restrict__ emb_j,
        unsigned char* __restrict__ Zi8, unsigned char* __restrict__ Zj8,
        float* __restrict__ w) {
    const int tid = threadIdx.x;
    if (blockIdx.x == 0 && tid == 0) {
        w[0] = 0.0f; w[1] = 0.0f;
        ((unsigned int*)w)[2] = 0u;
    }
    const int wave = tid >> 6, lane = tid & 63;
    const int row = blockIdx.x * 4 + wave;          // 0..8191
    const float* src; unsigned char* dst; int r;
    if (row < B_ROWS) { src = emb_i; dst = Zi8; r = row; }
    else              { src = emb_j; dst = Zj8; r = row - B_ROWS; }

    const float4* p = (const float4*)(src + (size_t)r * D_DIM);
    float4 v0 = p[lane], v1 = p[64 + lane], v2 = p[128 + lane], v3 = p[192 + lane];
    float s = v0.x*v0.x + v0.y*v0.y + v0.z*v0.z + v0.w*v0.w
            + v1.x*v1.x + v1.y*v1.y + v1.z*v1.z + v1.w*v1.w
            + v2.x*v2.x + v2.y*v2.y + v2.z*v2.z + v2.w*v2.w
            + v3.x*v3.x + v3.y*v3.y + v3.z*v3.z + v3.w*v3.w;
    #pragma unroll
    for (int m = 1; m < 64; m <<= 1) s += __shfl_xor(s, m, 64);
    const float inv = FP8_SCALE / fmaxf(sqrtf(s), 1e-12f);

    float4 a0 = {v0.x*inv, v0.y*inv, v0.z*inv, v0.w*inv};
    float4 a1 = {v1.x*inv, v1.y*inv, v1.z*inv, v1.w*inv};
    float4 a2 = {v2.x*inv, v2.y*inv, v2.z*inv, v2.w*inv};
    float4 a3 = {v3.x*inv, v3.y*inv, v3.z*inv, v3.w*inv};
    unsigned int* q = (unsigned int*)(dst + (size_t)r * D_DIM);
    q[lane]       = f2fp8x4(a0);
    q[64 + lane]  = f2fp8x4(a1);
    q[128 + lane] = f2fp8x4(a2);
    q[192 + lane] = f2fp8x4(a3);
}

// 128x128 block tile, BK=128 bytes (fp8), 4 waves (2x2): wave owns 64x64 =
// 2x2 MFMA tiles of 32x32x64 MX-fp8 (unit scales), two K-steps per LDS tile.
// Grid 32x32 = 1024 blocks. LDS 32 KB single-buffered.
//
// Register budget is the design driver: rounds 1-2 (64x128 wave tile: 128 acc
// + 48 frag VGPRs) spilled ~300 MB to scratch regardless of liveness
// structure. 64x64 tile: acc[2][2] f32x16 = 64 regs + 4 x v8i32 frags = 32
// regs + ~25 misc -> ~120, large slack. No launch_bounds occupancy force.
//
// LDS row = 128 B = 8 x 16-B pieces. XOR swizzle: logical piece c of row r sits
// at physical piece p = c ^ (r&7) (involution -> conflict-free ds_read_b128;
// numerics verified absmax 0.0 rounds 1-2). global_load_lds writes linearly
// (lane*16), so the *global* source piece is pre-swizzled; LDS stays linear.
__global__ __launch_bounds__(256, 2) void simloss_mfma_mxfp8_kernel(
        const unsigned char* __restrict__ Zi8,
        const unsigned char* __restrict__ Zj8,
        float* __restrict__ w, float* __restrict__ out) {
    __shared__ __align__(16) unsigned char lA[128 * 128];  // 16 KB (Zj rows)
    __shared__ __align__(16) unsigned char lB[128 * 128];  // 16 KB (Zi rows)
    __shared__ float rn[4], rp[4];

    const int tid  = threadIdx.x;
    const int lane = tid & 63;
    const int wave = tid >> 6;
    const int wy = wave >> 1, wx = wave & 1;
    const int rowBase = blockIdx.y * 128;   // a (Zj rows)
    const int colBase = blockIdx.x * 128;   // b (Zi rows)

    // --- staging: chunk = 8 rows x 128 B = 1 KB = one wave-load (16 B/lane).
    //     lane l -> LDS row (l>>3), physical piece (l&7); needs logical piece
    //     c = (l&7) ^ (row&7) = (l&7) ^ ((l>>3)&7) from global.
    //     Wave w stages A rows [32w, 32w+32) and B rows [32w, 32w+32).
    const int srow = lane >> 3;
    const int sc   = (lane & 7) ^ (srow & 7);
    const unsigned char* gA = Zj8 + (size_t)(rowBase + 32*wave + srow) * D_DIM + sc*16;
    const unsigned char* gB = Zi8 + (size_t)(colBase + 32*wave + srow) * D_DIM + sc*16;
    unsigned char* sA = lA + wave * 4096;
    unsigned char* sB = lB + wave * 4096;

    // --- fragment addressing: lane l holds row (l&31), k = (l>>5)*32 + 0..31
    //     (one MX scale-block). Logical piece for (kstep kk, 16B-half t) =
    //     kk*4 + (l>>5)*2 + t; physical = c ^ (row&7); row&7 == lane&7 since
    //     every fragment row base is a multiple of 8.
    const int lr = lane & 31;
    const int kh = lane >> 5;
    int off[2][2];
    #pragma unroll
    for (int kk = 0; kk < 2; ++kk)
        #pragma unroll
        for (int t = 0; t < 2; ++t)
            off[kk][t] = ((((kk << 2) + (kh << 1) + t) ^ (lane & 7)) << 4);
    const unsigned char* fA = lA + (wy * 64 + lr) * 128;   // + i*32*128
    const unsigned char* fB = lB + (wx * 64 + lr) * 128;   // + j*32*128

    f32x16 acc[2][2];
    #pragma unroll
    for (int i = 0; i < 2; ++i)
        #pragma unroll
        for (int j = 0; j < 2; ++j)
            #pragma unroll
            for (int r = 0; r < 16; ++r)
                acc[i][j][r] = 0.0f;

    for (int it = 0; it < 8; ++it) {
        __syncthreads();                    // prior readers done
        const int k0 = it * 128;
        #pragma unroll
        for (int n = 0; n < 4; ++n) {
            gload_lds16(gA + (size_t)(n*8) * D_DIM + k0, sA + n*1024);
            gload_lds16(gB + (size_t)(n*8) * D_DIM + k0, sB + n*1024);
        }
        __syncthreads();                    // staging visible (vmcnt drained)

        #pragma unroll
        for (int kk = 0; kk < 2; ++kk) {    // frags never cross a barrier
            i32x8 a0 = read_frag(fA,        off[kk][0], off[kk][1]);
            i32x8 a1 = read_frag(fA + 4096, off[kk][0], off[kk][1]);
            i32x8 b0 = read_frag(fB,        off[kk][0], off[kk][1]);
            i32x8 b1 = read_frag(fB + 4096, off[kk][0], off[kk][1]);
            acc[0][0] = MX_MFMA(a0, b0, acc[0][0]);
            acc[0][1] = MX_MFMA(a0, b1, acc[0][1]);
            acc[1][0] = MX_MFMA(a1, b0, acc[1][0]);
            acc[1][1] = MX_MFMA(a1, b1, acc[1][1]);
        }
    }

    // --- fused epilogue; 32x32 C layout: col=lane&31,
    //     row=(reg&3) + 8*(reg>>2) + 4*(lane>>5)   (verified rounds 1-2)
    float neg = 0.f, pos = 0.f;
    const int bc = colBase + wx * 64 + (lane & 31);
    #pragma unroll
    for (int i = 0; i < 2; ++i) {
        const int abase = rowBase + wy * 64 + i * 32 + 4 * kh;
        #pragma unroll
        for (int j = 0; j < 2; ++j) {
            const int b = bc + j * 32;
            #pragma unroll
            for (int r = 0; r < 16; ++r) {
                const int arow = abase + (r & 3) + 8 * (r >> 2);
                const float x = acc[i][j][r] * INV_S2 - TEMP;   // sim - T
                if (arow == b) pos += __logf(1.0f + __expf(-x));
                else           neg += __logf(1.0f + __expf(x));
            }
        }
    }
    #pragma unroll
    for (int o = 32; o > 0; o >>= 1) {
        neg += __shfl_down(neg, o, 64);
        pos += __shfl_down(pos, o, 64);
    }
    if (lane == 0) { rn[wave] = neg; rp[wave] = pos; }
    __syncthreads();
    if (tid == 0) {
        atomicAdd(&w[1], rn[0] + rn[1] + rn[2] + rn[3]);
        if (blockIdx.x == blockIdx.y)                    // tile holding diagonal
            atomicAdd(&w[0], rp[0] + rp[1] + rp[2] + rp[3]);
        __threadfence();
        unsigned int done = atomicAdd(((unsigned int*)w) + 2, 1u);
        if (done == gridDim.x * gridDim.y - 1) {         // last block finalizes
            const float psum = atomicAdd(&w[0], 0.0f);
            const float nsum = atomicAdd(&w[1], 0.0f);
            out[0] = 0.5f * (psum / (float)B_ROWS)
                   + 0.5f * (nsum / ((float)B_ROWS * (float)(B_ROWS - 1)));
        }
    }
}

extern "C" void kernel_launch(void* const* d_in, const int* in_sizes, int n_in,
                              void* d_out, int out_size, void* d_ws, size_t ws_size,
                              hipStream_t stream) {
    const float* emb_i = (const float*)d_in[0];
    const float* emb_j = (const float*)d_in[1];
    float* w = (float*)d_ws;
    unsigned char* Zi8 = (unsigned char*)(w + 16);
    unsigned char* Zj8 = Zi8 + (size_t)B_ROWS * D_DIM;
    float* out = (float*)d_out;

    norm_cast_kernel<<<2 * B_ROWS / 4, 256, 0, stream>>>(emb_i, emb_j, Zi8, Zj8, w);
    dim3 grid(B_ROWS / 128, B_ROWS / 128);   // 32 x 32 = 1024 blocks
    simloss_mfma_mxfp8_kernel<<<grid, 256, 0, stream>>>(Zi8, Zj8, w, out);
}

// Round 4
// 130.437 us; speedup vs baseline: 2.1825x; 1.6680x over previous
//
#include <hip/hip_runtime.h>
#include <math.h>

#define B_ROWS 4096
#define D_DIM  1024
static constexpr float TEMP = 0.2f;
static constexpr float FP8_SCALE = 16.0f;        // per-side scale before cast
static constexpr float INV_S2 = 1.0f / 256.0f;   // 1/SCALE^2: acc -> sim

typedef __attribute__((ext_vector_type(4)))  int   i32x4;
typedef __attribute__((ext_vector_type(8)))  int   i32x8;
typedef __attribute__((ext_vector_type(4)))  float f32x4;

// float -> OCP e4m3fn byte, RNE. Data path: |f| <= ~4, no NaN/inf.
__device__ inline unsigned char f2fp8(float f) {
    unsigned int u = __float_as_uint(f);
    unsigned int s = (u >> 24) & 0x80u;
    float af = fabsf(f);
    unsigned char b;
    if (af >= 0x1.0p-6f) {                 // normal e4m3 range
        unsigned int au = u & 0x7fffffffu;
        unsigned int lsb = (au >> 20) & 1u;
        au += 0x7ffffu + lsb;              // RNE into 3 mantissa bits
        int e = (int)(au >> 23) - 127 + 7;
        unsigned int m = (au >> 20) & 7u;
        if (e > 15 || (e == 15 && m > 6)) b = 0x7e;   // saturate 448
        else b = (unsigned char)((e << 3) | m);
    } else {                               // subnormal: quantum 2^-9
        int q = (int)rintf(af * 512.0f);
        b = (unsigned char)(q >= 8 ? 0x08 : q);
    }
    return (unsigned char)(b | s);
}

__device__ inline unsigned int f2fp8x4(float4 v) {
    return (unsigned int)f2fp8(v.x)
         | ((unsigned int)f2fp8(v.y) << 8)
         | ((unsigned int)f2fp8(v.z) << 16)
         | ((unsigned int)f2fp8(v.w) << 24);
}

// async global->LDS, 16 B/lane; LDS dest = wave-uniform base + lane*16
__device__ inline void gload_lds16(const unsigned char* g, unsigned char* l) {
    __builtin_amdgcn_global_load_lds(
        (const __attribute__((address_space(1))) unsigned int*)g,
        (__attribute__((address_space(3))) unsigned int*)l,
        16, 0, 0);
}

// read one 32-B fragment (two swizzled 16-B pieces) -> v8i32 MFMA operand
__device__ inline i32x8 read_frag(const unsigned char* p, int o0, int o1) {
    i32x4 lo = *(const i32x4*)(p + o0);
    i32x4 hi = *(const i32x4*)(p + o1);
    return __builtin_shufflevector(lo, hi, 0, 1, 2, 3, 4, 5, 6, 7);
}

// MX-scaled fp8 x fp8, K=128, unit E8M0 scales (0x7f = 2^0): fp8 GEMM at 2x
// rate with f32x4 accumulator (the m148-proven shape; 32x32x64's f32x16 acc
// spilled ~300 MB scratch in rounds 1-3 regardless of tile geometry).
#define MX_MFMA(A, Bv, C) __builtin_amdgcn_mfma_scale_f32_16x16x128_f8f6f4( \
    (A), (Bv), (C), 0, 0, 0, 0x7f7f7f7f, 0, 0x7f7f7f7f)

// ws layout: w[0]=pos acc, w[1]=neg acc, w[2]=finalize ticket (u32),
//            then Zi8 (4096x1024 fp8) at byte (w+16), Zj8 after.

// Wave-per-row normalize (fp32) + scale by 16 + cast to fp8 e4m3.
__global__ __launch_bounds__(256) void norm_cast_kernel(
        const float* __restrict__ emb_i, const float* __restrict__ emb_j,
        unsigned char* __restrict__ Zi8, unsigned char* __restrict__ Zj8,
        float* __restrict__ w) {
    const int tid = threadIdx.x;
    if (blockIdx.x == 0 && tid == 0) {
        w[0] = 0.0f; w[1] = 0.0f;
        ((unsigned int*)w)[2] = 0u;
    }
    const int wave = tid >> 6, lane = tid & 63;
    const int row = blockIdx.x * 4 + wave;          // 0..8191
    const float* src; unsigned char* dst; int r;
    if (row < B_ROWS) { src = emb_i; dst = Zi8; r = row; }
    else              { src = emb_j; dst = Zj8; r = row - B_ROWS; }

    const float4* p = (const float4*)(src + (size_t)r * D_DIM);
    float4 v0 = p[lane], v1 = p[64 + lane], v2 = p[128 + lane], v3 = p[192 + lane];
    float s = v0.x*v0.x + v0.y*v0.y + v0.z*v0.z + v0.w*v0.w
            + v1.x*v1.x + v1.y*v1.y + v1.z*v1.z + v1.w*v1.w
            + v2.x*v2.x + v2.y*v2.y + v2.z*v2.z + v2.w*v2.w
            + v3.x*v3.x + v3.y*v3.y + v3.z*v3.z + v3.w*v3.w;
    #pragma unroll
    for (int m = 1; m < 64; m <<= 1) s += __shfl_xor(s, m, 64);
    const float inv = FP8_SCALE / fmaxf(sqrtf(s), 1e-12f);

    float4 a0 = {v0.x*inv, v0.y*inv, v0.z*inv, v0.w*inv};
    float4 a1 = {v1.x*inv, v1.y*inv, v1.z*inv, v1.w*inv};
    float4 a2 = {v2.x*inv, v2.y*inv, v2.z*inv, v2.w*inv};
    float4 a3 = {v3.x*inv, v3.y*inv, v3.z*inv, v3.w*inv};
    unsigned int* q = (unsigned int*)(dst + (size_t)r * D_DIM);
    q[lane]       = f2fp8x4(a0);
    q[64 + lane]  = f2fp8x4(a1);
    q[128 + lane] = f2fp8x4(a2);
    q[192 + lane] = f2fp8x4(a3);
}

// 128x128 block tile, BK=128 bytes (fp8), 4 waves (2x2): wave owns 64x64 =
// 4x4 MFMA tiles of 16x16x128 MX-fp8 (unit scales), ONE K-step per LDS tile.
// Grid 32x32 = 1024 blocks. LDS 32 KB single-buffered. m148-style geometry:
// acc = f32x4[4][4] (64 regs, AGPR-friendly like round-0's clean f32x4[4][8]);
// live frags 4+4 x v8i32 = 64 VGPR, never crossing a barrier. No occupancy
// force in launch_bounds: no hard reg cap -> allocator never forced to spill.
//
// LDS row = 128 B = 8 x 16-B pieces. XOR swizzle: logical piece c of row r sits
// at physical piece p = c ^ (r&7) (involution; numerics verified rounds 1-3).
// global_load_lds writes linearly (lane*16), so the *global* source piece is
// pre-swizzled per lane; LDS stays linear.
__global__ __launch_bounds__(256) void simloss_mfma_mxfp8_kernel(
        const unsigned char* __restrict__ Zi8,
        const unsigned char* __restrict__ Zj8,
        float* __restrict__ w, float* __restrict__ out) {
    __shared__ __align__(16) unsigned char lA[128 * 128];  // 16 KB (Zj rows)
    __shared__ __align__(16) unsigned char lB[128 * 128];  // 16 KB (Zi rows)
    __shared__ float rn[4], rp[4];

    const int tid  = threadIdx.x;
    const int lane = tid & 63;
    const int wave = tid >> 6;
    const int wy = wave >> 1, wx = wave & 1;
    const int rowBase = blockIdx.y * 128;   // a (Zj rows)
    const int colBase = blockIdx.x * 128;   // b (Zi rows)

    // --- staging: chunk = 8 rows x 128 B = 1 KB = one wave-load (16 B/lane).
    //     lane l -> LDS row (l>>3), physical piece (l&7); needs logical piece
    //     c = (l&7) ^ (row&7) = (l&7) ^ (l>>3) from global.
    //     Wave w stages A rows [32w, 32w+32) and B rows [32w, 32w+32).
    const int srow = lane >> 3;
    const int sc   = (lane & 7) ^ srow;
    const unsigned char* gA = Zj8 + (size_t)(rowBase + 32*wave + srow) * D_DIM + sc*16;
    const unsigned char* gB = Zi8 + (size_t)(colBase + 32*wave + srow) * D_DIM + sc*16;
    unsigned char* sA = lA + wave * 4096;
    unsigned char* sB = lB + wave * 4096;

    // --- fragment addressing (16x16x128): lane l holds row (l&15),
    //     k = (l>>4)*32 + 0..31 -> logical pieces {2g, 2g+1}, g = l>>4.
    //     physical = logical ^ (row&7); row&7 == lane&7 since every fragment
    //     row base (wy*64 + i*16) is a multiple of 8 and row = base + (l&15).
    const int lr16 = lane & 15;
    const int g    = lane >> 4;
    const int o0 = ((((g << 1) + 0) ^ (lane & 7)) << 4);
    const int o1 = ((((g << 1) + 1) ^ (lane & 7)) << 4);
    const unsigned char* fA = lA + (wy * 64 + lr16) * 128;  // + i*16*128
    const unsigned char* fB = lB + (wx * 64 + lr16) * 128;  // + j*16*128

    f32x4 acc[4][4];
    #pragma unroll
    for (int i = 0; i < 4; ++i)
        #pragma unroll
        for (int j = 0; j < 4; ++j)
            acc[i][j] = (f32x4){0.f, 0.f, 0.f, 0.f};

    for (int it = 0; it < 8; ++it) {
        __syncthreads();                    // prior readers done
        const int k0 = it * 128;
        #pragma unroll
        for (int n = 0; n < 4; ++n) {
            gload_lds16(gA + (size_t)(n*8) * D_DIM + k0, sA + n*1024);
            gload_lds16(gB + (size_t)(n*8) * D_DIM + k0, sB + n*1024);
        }
        __syncthreads();                    // staging visible (vmcnt drained)

        i32x8 a0 = read_frag(fA,        o0, o1);
        i32x8 a1 = read_frag(fA + 2048, o0, o1);
        i32x8 a2 = read_frag(fA + 4096, o0, o1);
        i32x8 a3 = read_frag(fA + 6144, o0, o1);
        i32x8 b0 = read_frag(fB,        o0, o1);
        i32x8 b1 = read_frag(fB + 2048, o0, o1);
        i32x8 b2 = read_frag(fB + 4096, o0, o1);
        i32x8 b3 = read_frag(fB + 6144, o0, o1);
        acc[0][0] = MX_MFMA(a0, b0, acc[0][0]);
        acc[0][1] = MX_MFMA(a0, b1, acc[0][1]);
        acc[0][2] = MX_MFMA(a0, b2, acc[0][2]);
        acc[0][3] = MX_MFMA(a0, b3, acc[0][3]);
        acc[1][0] = MX_MFMA(a1, b0, acc[1][0]);
        acc[1][1] = MX_MFMA(a1, b1, acc[1][1]);
        acc[1][2] = MX_MFMA(a1, b2, acc[1][2]);
        acc[1][3] = MX_MFMA(a1, b3, acc[1][3]);
        acc[2][0] = MX_MFMA(a2, b0, acc[2][0]);
        acc[2][1] = MX_MFMA(a2, b1, acc[2][1]);
        acc[2][2] = MX_MFMA(a2, b2, acc[2][2]);
        acc[2][3] = MX_MFMA(a2, b3, acc[2][3]);
        acc[3][0] = MX_MFMA(a3, b0, acc[3][0]);
        acc[3][1] = MX_MFMA(a3, b1, acc[3][1]);
        acc[3][2] = MX_MFMA(a3, b2, acc[3][2]);
        acc[3][3] = MX_MFMA(a3, b3, acc[3][3]);
    }

    // --- fused epilogue; 16x16 C layout: col=lane&15, row=(lane>>4)*4+reg
    //     (round-0-verified mapping)
    float neg = 0.f, pos = 0.f;
    const int bc = colBase + wx * 64 + lr16;
    #pragma unroll
    for (int i = 0; i < 4; ++i) {
        const int abase = rowBase + wy * 64 + i * 16 + g * 4;
        #pragma unroll
        for (int j = 0; j < 4; ++j) {
            const int b = bc + j * 16;
            #pragma unroll
            for (int r = 0; r < 4; ++r) {
                const float x = acc[i][j][r] * INV_S2 - TEMP;   // sim - T
                if (abase + r == b) pos += __logf(1.0f + __expf(-x));
                else                neg += __logf(1.0f + __expf(x));
            }
        }
    }
    #pragma unroll
    for (int o = 32; o > 0; o >>= 1) {
        neg += __shfl_down(neg, o, 64);
        pos += __shfl_down(pos, o, 64);
    }
    if (lane == 0) { rn[wave] = neg; rp[wave] = pos; }
    __syncthreads();
    if (tid == 0) {
        atomicAdd(&w[1], rn[0] + rn[1] + rn[2] + rn[3]);
        if (blockIdx.x == blockIdx.y)                    // tile holding diagonal
            atomicAdd(&w[0], rp[0] + rp[1] + rp[2] + rp[3]);
        __threadfence();
        unsigned int done = atomicAdd(((unsigned int*)w) + 2, 1u);
        if (done == gridDim.x * gridDim.y - 1) {         // last block finalizes
            const float psum = atomicAdd(&w[0], 0.0f);
            const float nsum = atomicAdd(&w[1], 0.0f);
            out[0] = 0.5f * (psum / (float)B_ROWS)
                   + 0.5f * (nsum / ((float)B_ROWS * (float)(B_ROWS - 1)));
        }
    }
}

extern "C" void kernel_launch(void* const* d_in, const int* in_sizes, int n_in,
                              void* d_out, int out_size, void* d_ws, size_t ws_size,
                              hipStream_t stream) {
    const float* emb_i = (const float*)d_in[0];
    const float* emb_j = (const float*)d_in[1];
    float* w = (float*)d_ws;
    unsigned char* Zi8 = (unsigned char*)(w + 16);
    unsigned char* Zj8 = Zi8 + (size_t)B_ROWS * D_DIM;
    float* out = (float*)d_out;

    norm_cast_kernel<<<2 * B_ROWS / 4, 256, 0, stream>>>(emb_i, emb_j, Zi8, Zj8, w);
    dim3 grid(B_ROWS / 128, B_ROWS / 128);   // 32 x 32 = 1024 blocks
    simloss_mfma_mxfp8_kernel<<<grid, 256, 0, stream>>>(Zi8, Zj8, w, out);
}